// Round 11
// baseline (324.809 us; speedup 1.0000x reference)
//
#include <hip/hip_runtime.h>
#include <math.h>

#define G 20
#define N1 400
#define N2 760
#define CTXS 64
#define HID 640
#define NB 256
#define ITERS 100
#define PI_F 3.14159265358979323846f

// right edge (i,j), j<19: i<19 -> 39i+2j ; i==19 -> 741+j
// down  edge (i,j), i<19: j<19 -> 39i+2j+1 ; j==19 -> 39i+38
__device__ __forceinline__ int eR(int i, int j) { return (i < 19) ? (39 * i + 2 * j) : (741 + j); }
__device__ __forceinline__ int eD(int i, int j) { return (j < 19) ? (39 * i + 2 * j + 1) : (39 * i + 38); }

#define WAIT_LDS() asm volatile("s_waitcnt lgkmcnt(0)" ::: "memory")

#define LOAD_ROW20(dst, base) do {                                          \
    const float4* _rp = (const float4*)(base);                              \
    float4 _r0 = _rp[0], _r1 = _rp[1], _r2 = _rp[2], _r3 = _rp[3], _r4 = _rp[4]; \
    dst[0]=_r0.x; dst[1]=_r0.y; dst[2]=_r0.z; dst[3]=_r0.w;                 \
    dst[4]=_r1.x; dst[5]=_r1.y; dst[6]=_r1.z; dst[7]=_r1.w;                 \
    dst[8]=_r2.x; dst[9]=_r2.y; dst[10]=_r2.z; dst[11]=_r2.w;               \
    dst[12]=_r3.x; dst[13]=_r3.y; dst[14]=_r3.z; dst[15]=_r3.w;             \
    dst[16]=_r4.x; dst[17]=_r4.y; dst[18]=_r4.z; dst[19]=_r4.w; } while (0)

__device__ __forceinline__ void fma4v(float4& acc, float s, const float4& v) {
  acc.x = fmaf(s, v.x, acc.x); acc.y = fmaf(s, v.y, acc.y);
  acc.z = fmaf(s, v.z, acc.z); acc.w = fmaf(s, v.w, acc.w);
}

// Fused: MLP (R6, 4 waves) + 100 barrier-free Dykstra iterations on WAVE 0 ONLY.
// All private arrays use compile-time indices only (R4's spill bug avoided).
__global__ __launch_bounds__(256, 1) void spnet_kernel(
    const float* __restrict__ dmat, const float* __restrict__ W1,
    const float* __restrict__ b1v, const float* __restrict__ W2,
    const float* __restrict__ b2v, float* __restrict__ out)
{
  const int tid = threadIdx.x;
  const int bb  = blockIdx.x;

  __shared__ __align__(16) float sdrow[CTXS];
  __shared__ __align__(16) float sh[HID];
  __shared__ __align__(16) float st0[N2];     // t0 = -w
  __shared__ __align__(16) float srowT[N1];   // [j][i] = resid[i][j]
  __shared__ __align__(16) float sc1[N1];
  __shared__ __align__(16) float sc2T[N1];
  __shared__ __align__(16) float sd1[N1];
  __shared__ __align__(16) float szz[N1];     // Z[i][j]

  if (tid < CTXS) sdrow[tid] = dmat[bb * CTXS + tid];
  __syncthreads();

  // ---------- MLP layer 1 (R6 verbatim) ----------
  if (tid < HID / 4) {
    float4 acc = *(const float4*)(b1v + 4 * tid);
#pragma unroll 4
    for (int k = 0; k < CTXS; k += 4) {
      float4 h4 = *(const float4*)(sdrow + k);
      const float* wb = W1 + k * HID + 4 * tid;
      float4 w0 = *(const float4*)(wb);
      float4 w1 = *(const float4*)(wb + HID);
      float4 w2 = *(const float4*)(wb + 2 * HID);
      float4 w3 = *(const float4*)(wb + 3 * HID);
      fma4v(acc, h4.x, w0); fma4v(acc, h4.y, w1);
      fma4v(acc, h4.z, w2); fma4v(acc, h4.w, w3);
    }
    acc.x = acc.x > 0.f ? acc.x : 0.1f * acc.x;
    acc.y = acc.y > 0.f ? acc.y : 0.1f * acc.y;
    acc.z = acc.z > 0.f ? acc.z : 0.1f * acc.z;
    acc.w = acc.w > 0.f ? acc.w : 0.1f * acc.w;
    *(float4*)(sh + 4 * tid) = acc;
  }
  __syncthreads();

  // ---------- MLP layer 2 (R6 verbatim, unroll 2 = best measured) ----------
  if (tid < N2 / 4) {
    float4 acc = *(const float4*)(b2v + 4 * tid);
#pragma unroll 2
    for (int k = 0; k < HID; k += 4) {
      float4 h4 = *(const float4*)(sh + k);
      const float* wb = W2 + k * N2 + 4 * tid;
      float4 w0 = *(const float4*)(wb);
      float4 w1 = *(const float4*)(wb + N2);
      float4 w2 = *(const float4*)(wb + 2 * N2);
      float4 w3 = *(const float4*)(wb + 3 * N2);
      fma4v(acc, h4.x, w0); fma4v(acc, h4.y, w1);
      fma4v(acc, h4.z, w2); fma4v(acc, h4.w, w3);
    }
    float4 s; s.x = -acc.x; s.y = -acc.y; s.z = -acc.z; s.w = -acc.w;
    *(float4*)(st0 + 4 * tid) = s;
  }
  __syncthreads();   // st0 ready; LAST barrier in the kernel

  if (tid >= 64) return;   // waves 1-3 done; wave 0 runs the solver barrier-free
  const int ln = tid;

  // ---- edge/resid role: lanes 0..39, lane = (r, h), cols j0..j0+9 ----
  const int  r = ln >> 1, h = ln & 1, j0 = 10 * h;
  const bool eAct = (ln < 40);
  const bool rOK  = (r < 19);
  float tR[10], qR[10], tD[10], qD[10], yR[10], yD[10];
#pragma unroll
  for (int m = 0; m < 10; ++m) { tR[m]=0.f; qR[m]=0.f; tD[m]=0.f; qD[m]=0.f; yR[m]=0.f; yD[m]=0.f; }
  if (eAct) {
#pragma unroll
    for (int m = 0; m < 10; ++m) {
      int j = j0 + m;
      if ((h == 0) || (m < 9)) tR[m] = st0[eR(r, j)];   // j<19
      if (rOK)                 tD[m] = st0[eD(r, j)];
    }
  }

  // ---- DCT role: lanes 0..49, lane = (du, dg); tasks (c = 4dg+cc, u = du) ----
  const bool cAct = (ln < 50);
  int du = ln / 5; if (du > 9) du = 9;
  const int dg = ln % 5;
  const int k0 = 2 * du;
  float VA0[10], VA1[10], VC[20], S0v[4], S1v[4];
  {
    const float n0 = 0.22360679774997896f, nk = 0.31622776601683794f;
#pragma unroll
    for (int i = 0; i < 10; ++i) {
      VA0[i] = ((k0 == 0) ? n0 : nk) * cosf((float)(k0 * (2 * i + 1)) * (PI_F / 40.f));
      VA1[i] = nk * cosf((float)((k0 + 1) * (2 * i + 1)) * (PI_F / 40.f));
    }
#pragma unroll
    for (int k = 0; k < 20; ++k)
      VC[k] = ((k == 0) ? n0 : nk) * cosf((float)(k * (2 * du + 1)) * (PI_F / 40.f));
    float l0 = 2.f - 2.f * cosf((float)k0 * (PI_F / 20.f));
    float l1 = 2.f - 2.f * cosf((float)(k0 + 1) * (PI_F / 20.f));
#pragma unroll
    for (int cc = 0; cc < 4; ++cc) {
      int c = 4 * dg + cc;
      float lc = 2.f - 2.f * cosf((float)c * (PI_F / 20.f));
      S0v[cc] = (c == 0 && k0 == 0) ? 0.f : 1.f / (lc + l0);
      S1v[cc] = 1.f / (lc + l1);
    }
  }

  // ---- resid0: from t registers (q=0), write srowT ----
  {
    float tDup[10];
#pragma unroll
    for (int m = 0; m < 10; ++m) tDup[m] = __shfl(tD[m], (ln >= 2) ? ln - 2 : ln, 64);
    float tRl = __shfl(tR[9], (ln >= 1) ? ln - 1 : ln, 64);
    if (eAct) {
      float rr[10];
#pragma unroll
      for (int m = 0; m < 10; ++m) {
        float inR = (m == 0) ? ((h == 0) ? 0.f : tRl) : tR[m - 1];
        float inD = (r == 0) ? 0.f : tDup[m];
        rr[m] = tR[m] + tD[m] - inR - inD;
      }
      if (r == 0  && h == 0) rr[0] -= 1.f;   // b_eq[0] = 1
      if (r == 19 && h == 1) rr[9] += 1.f;   // b_eq[399] = -1
#pragma unroll
      for (int m = 0; m < 10; ++m) srowT[(j0 + m) * G + r] = rr[m];
    }
  }
  WAIT_LDS();

  for (int it = 0; it < ITERS; ++it) {
    // ---- A: sc1[k0][c], sc1[k0+1][c] = V-analysis of srowT rows ----
    if (cAct) {
#pragma unroll
      for (int cc = 0; cc < 4; ++cc) {
        const int c = 4 * dg + cc;
        float d_[20]; LOAD_ROW20(d_, srowT + 20 * c);
        float a0 = 0.f, a1 = 0.f;
#pragma unroll
        for (int i = 0; i < 10; ++i) {
          float e_ = d_[i] + d_[19 - i], o_ = d_[i] - d_[19 - i];
          a0 = fmaf(VA0[i], e_, a0);
          a1 = fmaf(VA1[i], o_, a1);
        }
        sc1[k0 * G + c] = a0;
        sc1[(k0 + 1) * G + c] = a1;
      }
    }
    WAIT_LDS();

    // ---- B: sc2T = S * analysis of sc1 rows ----
    if (cAct) {
#pragma unroll
      for (int cc = 0; cc < 4; ++cc) {
        const int c = 4 * dg + cc;
        float d_[20]; LOAD_ROW20(d_, sc1 + 20 * c);
        float a0 = 0.f, a1 = 0.f;
#pragma unroll
        for (int j = 0; j < 10; ++j) {
          float e_ = d_[j] + d_[19 - j], o_ = d_[j] - d_[19 - j];
          a0 = fmaf(VA0[j], e_, a0);
          a1 = fmaf(VA1[j], o_, a1);
        }
        sc2T[k0 * G + c] = a0 * S0v[cc];
        sc2T[(k0 + 1) * G + c] = a1 * S1v[cc];
      }
    }
    WAIT_LDS();

    // ---- C: sd1[u][c], sd1[19-u][c] = synthesis (k-parity E/O) ----
    if (cAct) {
#pragma unroll
      for (int cc = 0; cc < 4; ++cc) {
        const int c = 4 * dg + cc;
        float d_[20]; LOAD_ROW20(d_, sc2T + 20 * c);
        float E = 0.f, O = 0.f;
#pragma unroll
        for (int m = 0; m < 10; ++m) {
          E = fmaf(VC[2 * m], d_[2 * m], E);
          O = fmaf(VC[2 * m + 1], d_[2 * m + 1], O);
        }
        sd1[du * G + c] = E + O;
        sd1[(19 - du) * G + c] = E - O;
      }
    }
    WAIT_LDS();

    // ---- D: szz[c][u], szz[c][19-u] = synthesis ----
    if (cAct) {
#pragma unroll
      for (int cc = 0; cc < 4; ++cc) {
        const int c = 4 * dg + cc;
        float d_[20]; LOAD_ROW20(d_, sd1 + 20 * c);
        float E = 0.f, O = 0.f;
#pragma unroll
        for (int m = 0; m < 10; ++m) {
          E = fmaf(VC[2 * m], d_[2 * m], E);
          O = fmaf(VC[2 * m + 1], d_[2 * m + 1], O);
        }
        szz[c * G + du] = E + O;
        szz[c * G + (19 - du)] = E - O;
      }
    }
    WAIT_LDS();

    // ---- EDGE update (registers) + fused next-iter resid ----
    if (eAct) {
      const int zb = r * G + j0;
      float zi[11], zd[10];
#pragma unroll
      for (int m = 0; m < 10; ++m) zi[m] = szz[zb + m];
      { int a10 = zb + 10; if (a10 > 399) a10 = 399; zi[10] = szz[a10]; }
      const int zb2 = (rOK ? (r + 1) : r) * G + j0;
#pragma unroll
      for (int m = 0; m < 10; ++m) zd[m] = szz[zb2 + m];
#pragma unroll
      for (int m = 0; m < 10; ++m) {          // right edges (j = j0+m)
        bool vR = (h == 0) || (m < 9);
        float pn = vR ? (zi[m] - zi[m + 1]) : 0.f;
        float t2 = tR[m] - pn + qR[m];
        float yn = fmaxf(t2, 0.f);
        qR[m] = t2 - yn; yR[m] = yn; tR[m] = yn + pn;
      }
#pragma unroll
      for (int m = 0; m < 10; ++m) {          // down edges
        float pn = rOK ? (zi[m] - zd[m]) : 0.f;
        float t2 = tD[m] - pn + qD[m];
        float yn = fmaxf(t2, 0.f);
        qD[m] = t2 - yn; yD[m] = yn; tD[m] = yn + pn;
      }
    }
    if (it < ITERS - 1) {
      float tDup[10];
#pragma unroll
      for (int m = 0; m < 10; ++m) tDup[m] = __shfl(tD[m], (ln >= 2) ? ln - 2 : ln, 64);
      float tRl = __shfl(tR[9], (ln >= 1) ? ln - 1 : ln, 64);
      if (eAct) {
        float rr[10];
#pragma unroll
        for (int m = 0; m < 10; ++m) {
          float inR = (m == 0) ? ((h == 0) ? 0.f : tRl) : tR[m - 1];
          float inD = (r == 0) ? 0.f : tDup[m];
          rr[m] = tR[m] + tD[m] - inR - inD;
        }
        if (r == 0  && h == 0) rr[0] -= 1.f;
        if (r == 19 && h == 1) rr[9] += 1.f;
#pragma unroll
        for (int m = 0; m < 10; ++m) srowT[(j0 + m) * G + r] = rr[m];
      }
      WAIT_LDS();
    }
  }

  // ---- output (y = yn of final edge update) ----
  if (eAct) {
    float* mine = out + bb * N2;
#pragma unroll
    for (int m = 0; m < 10; ++m) {
      int j = j0 + m;
      if ((h == 0) || (m < 9)) mine[eR(r, j)] = yR[m];
      if (rOK)                 mine[eD(r, j)] = yD[m];
    }
  }
}

extern "C" void kernel_launch(void* const* d_in, const int* in_sizes, int n_in,
                              void* d_out, int out_size, void* d_ws, size_t ws_size,
                              hipStream_t stream) {
  const float* d   = (const float*)d_in[0];
  const float* W1  = (const float*)d_in[1];
  const float* b1  = (const float*)d_in[2];
  const float* W2  = (const float*)d_in[3];
  const float* b2  = (const float*)d_in[4];
  // d_in[5] = A, d_in[6] = b_eq: grid structure hardcoded
  float* out = (float*)d_out;
  spnet_kernel<<<NB, 256, 0, stream>>>(d, W1, b1, W2, b2, out);
}